// Round 9
// baseline (422.325 us; speedup 1.0000x reference)
//
#include <hip/hip_runtime.h>
#include <math.h>

// Problem constants (B=16, C=2, H=1024, W=1024)
#define HW   (1024 * 1024)          // H*W = 1M (power of two)
#define NPIX (16 * HW)              // B*H*W = 16,777,216
#define NGRP (NPIX / 4)             // float4 groups over pixel space = 4,194,304

constexpr int THREADS   = 256;
constexpr int NBLK      = 2048;                    // 8 blocks/CU -> whole grid co-resident
constexpr int TOTALTHR  = NBLK * THREADS;          // 524,288 threads
constexpr int ITERS     = NGRP / TOTALTHR;         // 8 float4-groups per thread
static_assert(ITERS * TOTALTHR == NGRP, "exact tiling");
static_assert((ITERS & 1) == 0, "ping-pong needs even ITERS");
static_assert(NBLK % THREADS == 0, "fused finalize: 8 partials per thread");
// Per-iteration pointer strides are uniform compile-time constants because
// 4*TOTALTHR (2^21) is a multiple of HW (2^20).
constexpr int MS_STR = 2 * HW;   // mask/scale stride per iteration (elements)
constexpr int PT_STR = 4 * HW;   // pred/truth stride per iteration (elements)

typedef float v4f __attribute__((ext_vector_type(4)));

// ALL loads non-temporal. R3/R4 (all-cacheable)=129us, R7 (2/6 cacheable)=100us,
// R6 (all-nt)<77.5us, with FETCH_SIZE byte-identical (196.6MB) in every case.
// => nt's win is NOT L3 behavior; it is skipping L1/L2 allocation for six
// 2MB-strided streams that would otherwise thrash the 4MiB/XCD L2 pipeline.
__device__ __forceinline__ v4f ntload(const float* p) {
    return __builtin_nontemporal_load((const v4f*)p);
}

__device__ __forceinline__ float fast_sigmoid(float x) {
    return __builtin_amdgcn_rcpf(1.0f + __expf(-x));
}

__device__ __forceinline__ float elem_loss(float x0, float x1, float t0, float t1) {
    float p0 = fast_sigmoid(x0);
    float p1 = fast_sigmoid(x1);
    // p0,p1 in (0,1): e^p in (1,e), no stabilization needed
    float lse = __logf(__expf(p0) + __expf(p1));
    return (t0 + t1) * lse - (t0 * p0 + t1 * p1);
}

// True ping-pong software pipeline (validated R6: kernel dropped under the
// 77.5-us fill dispatches). Two named register sets, no rotation copies, full
// unroll with static guards — collapse is dataflow-illegal, so each wave keeps
// ~6 loads (6 KB) outstanding through every compute phase.
// Finalize fused via last-block-done (counter at ws[2*NBLK], cleared each
// iteration by a 4-byte hipMemsetAsync) — removes one dispatch.
__global__ __launch_bounds__(THREADS, 4) void xy_loss_main(
    const float* __restrict__ mask,   // [B,1,H,W]
    const float* __restrict__ scale,  // [B,1,H,W]
    const float* __restrict__ pred,   // [B,2,H,W]
    const float* __restrict__ truth,  // [B,2,H,W]
    float* __restrict__ ws,           // [0..NBLK) s1, [NBLK..2NBLK) s2, [2NBLK] counter
    float* __restrict__ out)
{
    const int g0 = blockIdx.x * THREADS + threadIdx.x;
    const int i0 = g0 << 2;                  // flat pixel index (b*HW + hw)
    const int b0 = i0 + (i0 & ~(HW - 1));    // b*2*HW + hw

    const float* pm = mask  + i0;
    const float* ps = scale + i0;
    const float* pp = pred  + b0;
    const float* pt = truth + b0;

    v4f ax0, ax1, at0, at1, amk, asc;   // batch A registers
    v4f bx0, bx1, bt0, bt1, bmk, bsc;   // batch B registers

#define LOAD_A(K) do { \
        ax0 = ntload(pp + (K) * PT_STR); \
        ax1 = ntload(pp + (K) * PT_STR + HW); \
        at0 = ntload(pt + (K) * PT_STR); \
        at1 = ntload(pt + (K) * PT_STR + HW); \
        amk = ntload(pm + (K) * MS_STR); \
        asc = ntload(ps + (K) * MS_STR); \
    } while (0)

#define LOAD_B(K) do { \
        bx0 = ntload(pp + (K) * PT_STR); \
        bx1 = ntload(pp + (K) * PT_STR + HW); \
        bt0 = ntload(pt + (K) * PT_STR); \
        bt1 = ntload(pt + (K) * PT_STR + HW); \
        bmk = ntload(pm + (K) * MS_STR); \
        bsc = ntload(ps + (K) * MS_STR); \
    } while (0)

#define CONSUME_A() do { \
        s1 += elem_loss(ax0.x, ax1.x, at0.x, at1.x) \
            + elem_loss(ax0.y, ax1.y, at0.y, at1.y) \
            + elem_loss(ax0.z, ax1.z, at0.z, at1.z) \
            + elem_loss(ax0.w, ax1.w, at0.w, at1.w); \
        s2 += amk.x * asc.x + amk.y * asc.y + amk.z * asc.z + amk.w * asc.w; \
    } while (0)

#define CONSUME_B() do { \
        s1 += elem_loss(bx0.x, bx1.x, bt0.x, bt1.x) \
            + elem_loss(bx0.y, bx1.y, bt0.y, bt1.y) \
            + elem_loss(bx0.z, bx1.z, bt0.z, bt1.z) \
            + elem_loss(bx0.w, bx1.w, bt0.w, bt1.w); \
        s2 += bmk.x * bsc.x + bmk.y * bsc.y + bmk.z * bsc.z + bmk.w * bsc.w; \
    } while (0)

    float s1 = 0.0f, s2 = 0.0f;

    LOAD_A(0);
    #pragma unroll
    for (int k = 0; k < ITERS; k += 2) {
        LOAD_B(k + 1);                       // issue next batch before consuming A
        CONSUME_A();
        if (k + 2 < ITERS) LOAD_A(k + 2);    // static guard after full unroll
        CONSUME_B();
    }

#undef LOAD_A
#undef LOAD_B
#undef CONSUME_A
#undef CONSUME_B

    // wave64 shuffle reduction
    #pragma unroll
    for (int off = 32; off > 0; off >>= 1) {
        s1 += __shfl_down(s1, off, 64);
        s2 += __shfl_down(s2, off, 64);
    }

    __shared__ float ls1[4], ls2[4];
    __shared__ unsigned last_flag;
    const int lane = threadIdx.x & 63;
    const int wv   = threadIdx.x >> 6;
    if (lane == 0) { ls1[wv] = s1; ls2[wv] = s2; }
    __syncthreads();

    if (threadIdx.x == 0) {
        ws[blockIdx.x]        = ls1[0] + ls1[1] + ls1[2] + ls1[3];
        ws[NBLK + blockIdx.x] = ls2[0] + ls2[1] + ls2[2] + ls2[3];
        __threadfence();                                   // release partials
        unsigned done = atomicAdd((unsigned*)(ws + 2 * NBLK), 1u);  // device scope
        last_flag = (done == (unsigned)(NBLK - 1)) ? 1u : 0u;
    }
    __syncthreads();

    if (last_flag) {
        __threadfence();                                   // acquire partials
        const int tid = threadIdx.x;
        float a = 0.0f, b = 0.0f;
        #pragma unroll
        for (int k = 0; k < NBLK / THREADS; ++k) {         // deterministic tree
            a += ws[tid * (NBLK / THREADS) + k];
            b += ws[NBLK + tid * (NBLK / THREADS) + k];
        }
        #pragma unroll
        for (int off = 32; off > 0; off >>= 1) {
            a += __shfl_down(a, off, 64);
            b += __shfl_down(b, off, 64);
        }
        __shared__ float la[4], lb[4];
        if (lane == 0) { la[wv] = a; lb[wv] = b; }
        __syncthreads();
        if (tid == 0) {
            float t1 = la[0] + la[1] + la[2] + la[3];
            float t2 = lb[0] + lb[1] + lb[2] + lb[3];
            out[0] = t1 * t2 * (1.0f / (float)NPIX);
        }
    }
}

extern "C" void kernel_launch(void* const* d_in, const int* in_sizes, int n_in,
                              void* d_out, int out_size, void* d_ws, size_t ws_size,
                              hipStream_t stream) {
    const float* mask  = (const float*)d_in[0];  // object_mask    [16,1,1024,1024]
    const float* scale = (const float*)d_in[1];  // box_loss_scale [16,1,1024,1024]
    const float* pred  = (const float*)d_in[2];  // predict_xy     [16,2,1024,1024]
    const float* truth = (const float*)d_in[3];  // true_xy        [16,2,1024,1024]
    float* out = (float*)d_out;
    float* ws  = (float*)d_ws;   // 2*NBLK float partials + 1 uint counter

    // Clear completion counter (ws may be re-poisoned between iterations).
    // 4-byte async memset is graph-capture-legal and replaces the whole
    // xy_finalize dispatch.
    hipMemsetAsync(ws + 2 * NBLK, 0, sizeof(unsigned), stream);
    xy_loss_main<<<NBLK, THREADS, 0, stream>>>(mask, scale, pred, truth, ws, out);
}

// Round 10
// 328.884 us; speedup vs baseline: 1.2841x; 1.2841x over previous
//
#include <hip/hip_runtime.h>
#include <math.h>

// Problem constants (B=16, C=2, H=1024, W=1024)
#define HW   (1024 * 1024)          // H*W = 1M (power of two)
#define NPIX (16 * HW)              // B*H*W = 16,777,216
#define NGRP (NPIX / 4)             // float4 groups over pixel space = 4,194,304

constexpr int THREADS   = 256;
constexpr int NBLK      = 2048;                    // 8 blocks/CU, grid-stride
constexpr int TOTALTHR  = NBLK * THREADS;          // 524,288 threads
constexpr int ITERS     = NGRP / TOTALTHR;         // 8 float4-groups per thread
static_assert(ITERS * TOTALTHR == NGRP, "exact tiling");
static_assert((ITERS & 1) == 0, "ping-pong needs even ITERS");
// Per-iteration pointer strides are uniform compile-time constants because
// 4*TOTALTHR (2^21) is a multiple of HW (2^20).
constexpr int MS_STR = 2 * HW;   // mask/scale stride per iteration (elements)
constexpr int PT_STR = 4 * HW;   // pred/truth stride per iteration (elements)

typedef float v4f __attribute__((ext_vector_type(4)));

// ALL loads non-temporal. Measured ladder: all-cacheable=129us (R3/R4),
// 2/6-cacheable=100us (R7), all-nt<77.5us (R6), FETCH_SIZE byte-identical
// (196.6MB) in every case => nt's win is the request path (skipping L1/L2
// allocation for six 2MB-strided streams), not L3 policy. Do not revisit.
__device__ __forceinline__ v4f ntload(const float* p) {
    return __builtin_nontemporal_load((const v4f*)p);
}

__device__ __forceinline__ float fast_sigmoid(float x) {
    return __builtin_amdgcn_rcpf(1.0f + __expf(-x));
}

__device__ __forceinline__ float elem_loss(float x0, float x1, float t0, float t1) {
    float p0 = fast_sigmoid(x0);
    float p1 = fast_sigmoid(x1);
    // p0,p1 in (0,1): e^p in (1,e), no stabilization needed
    float lse = __logf(__expf(p0) + __expf(p1));
    return (t0 + t1) * lse - (t0 * p0 + t1 * p1);
}

// True ping-pong software pipeline (R6-validated best: kernel under the
// 77.5-us fill dispatches, bench 324.8). Two named register sets, no rotation
// copies, full unroll with static guards — collapse is dataflow-illegal, so
// each wave keeps ~6 loads (6 KB) outstanding through every compute phase.
// R9 lesson: do NOT fuse the finalize via device-scope fence/atomic — the
// per-block agent-scope release (L2 writeback) injected 2048 pipeline flushes
// and made the kernel 2.3x slower. Two dispatches is the right structure.
__global__ __launch_bounds__(THREADS, 4) void xy_loss_main(
    const float* __restrict__ mask,   // [B,1,H,W]
    const float* __restrict__ scale,  // [B,1,H,W]
    const float* __restrict__ pred,   // [B,2,H,W]
    const float* __restrict__ truth,  // [B,2,H,W]
    float* __restrict__ ws)           // [0..NBLK): S1 parts, [NBLK..2*NBLK): S2 parts
{
    const int g0 = blockIdx.x * THREADS + threadIdx.x;
    const int i0 = g0 << 2;                  // flat pixel index (b*HW + hw)
    const int b0 = i0 + (i0 & ~(HW - 1));    // b*2*HW + hw

    const float* pm = mask  + i0;
    const float* ps = scale + i0;
    const float* pp = pred  + b0;
    const float* pt = truth + b0;

    v4f ax0, ax1, at0, at1, amk, asc;   // batch A registers
    v4f bx0, bx1, bt0, bt1, bmk, bsc;   // batch B registers

#define LOAD_A(K) do { \
        ax0 = ntload(pp + (K) * PT_STR); \
        ax1 = ntload(pp + (K) * PT_STR + HW); \
        at0 = ntload(pt + (K) * PT_STR); \
        at1 = ntload(pt + (K) * PT_STR + HW); \
        amk = ntload(pm + (K) * MS_STR); \
        asc = ntload(ps + (K) * MS_STR); \
    } while (0)

#define LOAD_B(K) do { \
        bx0 = ntload(pp + (K) * PT_STR); \
        bx1 = ntload(pp + (K) * PT_STR + HW); \
        bt0 = ntload(pt + (K) * PT_STR); \
        bt1 = ntload(pt + (K) * PT_STR + HW); \
        bmk = ntload(pm + (K) * MS_STR); \
        bsc = ntload(ps + (K) * MS_STR); \
    } while (0)

#define CONSUME_A() do { \
        s1 += elem_loss(ax0.x, ax1.x, at0.x, at1.x) \
            + elem_loss(ax0.y, ax1.y, at0.y, at1.y) \
            + elem_loss(ax0.z, ax1.z, at0.z, at1.z) \
            + elem_loss(ax0.w, ax1.w, at0.w, at1.w); \
        s2 += amk.x * asc.x + amk.y * asc.y + amk.z * asc.z + amk.w * asc.w; \
    } while (0)

#define CONSUME_B() do { \
        s1 += elem_loss(bx0.x, bx1.x, bt0.x, bt1.x) \
            + elem_loss(bx0.y, bx1.y, bt0.y, bt1.y) \
            + elem_loss(bx0.z, bx1.z, bt0.z, bt1.z) \
            + elem_loss(bx0.w, bx1.w, bt0.w, bt1.w); \
        s2 += bmk.x * bsc.x + bmk.y * bsc.y + bmk.z * bsc.z + bmk.w * bsc.w; \
    } while (0)

    float s1 = 0.0f, s2 = 0.0f;

    LOAD_A(0);
    #pragma unroll
    for (int k = 0; k < ITERS; k += 2) {
        LOAD_B(k + 1);                       // issue next batch before consuming A
        CONSUME_A();
        if (k + 2 < ITERS) LOAD_A(k + 2);    // static guard after full unroll
        CONSUME_B();
    }

#undef LOAD_A
#undef LOAD_B
#undef CONSUME_A
#undef CONSUME_B

    // wave64 shuffle reduction
    #pragma unroll
    for (int off = 32; off > 0; off >>= 1) {
        s1 += __shfl_down(s1, off, 64);
        s2 += __shfl_down(s2, off, 64);
    }

    __shared__ float ls1[4], ls2[4];
    const int lane = threadIdx.x & 63;
    const int wv   = threadIdx.x >> 6;
    if (lane == 0) { ls1[wv] = s1; ls2[wv] = s2; }
    __syncthreads();

    if (threadIdx.x == 0) {
        ws[blockIdx.x]        = ls1[0] + ls1[1] + ls1[2] + ls1[3];
        ws[NBLK + blockIdx.x] = ls2[0] + ls2[1] + ls2[2] + ls2[3];
    }
}

__global__ __launch_bounds__(1024) void xy_finalize(
    const float* __restrict__ ws, float* __restrict__ out)
{
    const int tid = threadIdx.x;
    // NBLK = 2048 partials per array, 1024 threads -> 2 each
    float a = ws[tid]        + ws[tid + 1024];
    float b = ws[NBLK + tid] + ws[NBLK + tid + 1024];

    #pragma unroll
    for (int off = 32; off > 0; off >>= 1) {
        a += __shfl_down(a, off, 64);
        b += __shfl_down(b, off, 64);
    }
    __shared__ float la[16], lb[16];
    const int lane = tid & 63;
    const int wv   = tid >> 6;
    if (lane == 0) { la[wv] = a; lb[wv] = b; }
    __syncthreads();
    if (tid == 0) {
        float s1 = 0.0f, s2 = 0.0f;
        #pragma unroll
        for (int w = 0; w < 16; ++w) { s1 += la[w]; s2 += lb[w]; }
        out[0] = s1 * s2 * (1.0f / (float)NPIX);
    }
}

extern "C" void kernel_launch(void* const* d_in, const int* in_sizes, int n_in,
                              void* d_out, int out_size, void* d_ws, size_t ws_size,
                              hipStream_t stream) {
    const float* mask  = (const float*)d_in[0];  // object_mask    [16,1,1024,1024]
    const float* scale = (const float*)d_in[1];  // box_loss_scale [16,1,1024,1024]
    const float* pred  = (const float*)d_in[2];  // predict_xy     [16,2,1024,1024]
    const float* truth = (const float*)d_in[3];  // true_xy        [16,2,1024,1024]
    float* out = (float*)d_out;
    float* ws  = (float*)d_ws;                   // 2*NBLK floats = 16 KB of partials

    xy_loss_main<<<NBLK, THREADS, 0, stream>>>(mask, scale, pred, truth, ws);
    xy_finalize<<<1, 1024, 0, stream>>>(ws, out);
}